// Round 10
// baseline (1266.154 us; speedup 1.0000x reference)
//
#include <hip/hip_runtime.h>
#include <math.h>

// ---------------------------------------------------------------------------
// Lstm_60748017434907 — R14: R10 champion + L0 weight prefetch into the spin.
//
// R13 post-mortem: removing work from L0 (xg graft) REGRESSED 278->435us.
// Lessons: VALUBusy is partly poll-spin-generated (the 80us "work invariant"
// was circular); the phase loop is a publish/poll equilibrium — R8/R9/R13
// all perturbed intra-phase timing and all regressed. Only R10's fan-out
// change helped. Specific mechanism for R13: the x-load's vmcnt wait was a
// ~0.3us pre-poll backoff; removing it makes threads hammer polls before
// data can exist, adding fabric pressure at publish time.
//
// R14 changes NOTHING about R10's poll/stage/barrier/publish structure.
// Single graft: L0's per-phase weight fragments (wi,wr: 32 float4/lane,
// currently compiler-remat'd AFTER the barrier, ~1.5-1.9us of L2 latency on
// the h1 critical chain) are reloaded at the TOP of each phase and pinned
// ("+v" asm) BEFORE the polls: their latency hides under the ~2us spin, and
// post-barrier L0 compute runs register-resident, publishing h1 earlier.
// Pin lifetime = one phase (not the loop) => ~190 live VGPR, fits the 256
// budget at 2 waves/EU; per-phase spill would look expensive to the
// allocator's own cost model (unlike the whole-loop lifetimes it refused in
// R5/R6/R8). L1 stays remat'd — h2 has a full phase of slack, off-chain.
// Side effect: the pins' waitcnt LENGTHENS the pre-poll backoff — the safe
// direction per the R13 mechanism.
//
// Protocol unchanged: nrep=8 replicas (measured optimum), data-as-flag
// (0xAA poison, enc=+0x55555555), relaxed agent-scope u64 polls, no fences,
// no memset, GUARD-bounded spins.
// ---------------------------------------------------------------------------

#define NBLK 256
#define TPB  512
#define HDIM 1024
#define SEQ  64
#define CHAIN (SEQ * HDIM)
#define GUARD (1L << 20)
#define POISON 0xAAAAAAAAu
#define ENCOFF 0x55555555u

#define FMA4(A, W, Hv)                                                         \
  do {                                                                         \
    (A).x = fmaf((W).x, (Hv).x, (A).x);                                        \
    (A).y = fmaf((W).y, (Hv).y, (A).y);                                        \
    (A).z = fmaf((W).z, (Hv).z, (A).z);                                        \
    (A).w = fmaf((W).w, (Hv).w, (A).w);                                        \
  } while (0)

// claims to modify the value: forces materialization HERE and forbids remat
#define PIN4(V)                                                                \
  asm volatile("" : "+v"((V).x), "+v"((V).y), "+v"((V).z), "+v"((V).w))

__device__ __forceinline__ float sigmoidf_(float v) {
  return 1.0f / (1.0f + expf(-v));
}
__device__ __forceinline__ float hsum4(float4 a) {
  return (a.x + a.y) + (a.z + a.w);
}
__device__ __forceinline__ float wave_sum(float v) {
#pragma unroll
  for (int m = 32; m >= 1; m >>= 1) v += __shfl_xor(v, m, 64);
  return v;
}

__device__ __forceinline__ void st_u32(unsigned* p, unsigned v) {
  __hip_atomic_store(p, v, __ATOMIC_RELAXED, __HIP_MEMORY_SCOPE_AGENT);
}
__device__ __forceinline__ unsigned enc(float v) {
  return __float_as_uint(v) + ENCOFF;
}
__device__ __forceinline__ float dec(unsigned u) {
  return __uint_as_float(u - ENCOFF);
}
// poll one u64 record-pair until both halves != poison
__device__ __forceinline__ float2 poll2(const unsigned* p) {
  const unsigned long long* pp = (const unsigned long long*)p;
  unsigned lo, hi;
  long g = 0;
  for (;;) {
    unsigned long long u =
        __hip_atomic_load(pp, __ATOMIC_RELAXED, __HIP_MEMORY_SCOPE_AGENT);
    lo = (unsigned)u;
    hi = (unsigned)(u >> 32);
    if ((lo != POISON) & (hi != POISON)) break;
    __builtin_amdgcn_s_sleep(1);
    if (++g > GUARD) break;  // deadlock -> bounded wrong answer, no hang
  }
  asm volatile("" ::: "memory");
  return make_float2(dec(lo), dec(hi));
}

__global__ void __launch_bounds__(TPB, 2) lstm_persist(
    const float* __restrict__ x,
    const float* __restrict__ Wih0, const float* __restrict__ Whh0,
    const float* __restrict__ bih0, const float* __restrict__ bhh0,
    const float* __restrict__ Wih1, const float* __restrict__ Whh1,
    const float* __restrict__ bih1, const float* __restrict__ bhh1,
    const float* __restrict__ W1, const float* __restrict__ b1,
    const float* __restrict__ W2, const float* __restrict__ b2,
    float* __restrict__ out, unsigned* ws, int nrep) {
  __shared__ float sA[2][HDIM];  // h1[p-1]
  __shared__ float sB[2][HDIM];  // h2[p-2]
  __shared__ float sX[2][HDIM];  // x[p]

  // ws layout (u32): h1rep[nrep][CHAIN] | h2rep[nrep][CHAIN] | fcb[64*512]
  unsigned* h1rep = ws;
  unsigned* h2rep = ws + (size_t)nrep * CHAIN;
  unsigned* fcb = ws + 2ull * (size_t)nrep * CHAIN;

  const int tid = threadIdx.x;
  const int b = blockIdx.x;
  const int lane = tid & 63;
  const int q = tid >> 6;             // 0..7
  const int L = q >> 2;               // 0: layer0 waves, 1: layer1 waves
  const int elem = (b << 2) + (q & 3);

  // this block's poll replica (nrep pow2; nrep=8 => reader set per XCD)
  const int rep = b & (nrep - 1);
  unsigned* h1r = h1rep + (size_t)rep * CHAIN;
  unsigned* h2r = h2rep + (size_t)rep * CHAIN;

  // ---- L1 weights: pre-loop load, compiler remats post-barrier (h2 has a
  // full phase of slack — off the critical chain; accepted) ----
  float4 wi1[4][4], wr1[4][4];
  float bias[4];
  {
    const float* bi = L ? bih1 : bih0;
    const float* bh = L ? bhh1 : bhh0;
#pragma unroll
    for (int g = 0; g < 4; ++g) {
      const int row = (g << 10) + elem;
      bias[g] = bi[row] + bh[row];
    }
  }
  if (L == 1) {
#pragma unroll
    for (int g = 0; g < 4; ++g) {
      const int row = (g << 10) + elem;
      const float4* pi = (const float4*)(Wih1 + (size_t)row * HDIM);
      const float4* pr = (const float4*)(Whh1 + (size_t)row * HDIM);
#pragma unroll
      for (int k = 0; k < 4; ++k) {
        wi1[g][k] = pi[(k << 6) + lane];
        wr1[g][k] = pr[(k << 6) + lane];
      }
    }
  }

  float cell = 0.0f;  // wave-uniform cell state (this wave's layer+elem)

  // ================= pipelined phases p = 0..64 =================
  for (int p = 0; p <= SEQ; ++p) {
    const int pb = p & 1;
    // x[p] issued first (latency overlaps polls) — exactly as R10.
    float2 xv = make_float2(0, 0);
    if (p < SEQ)
      xv = ((const float2*)x)[(size_t)(p * 256 + 255) * 512 + tid];

    // ---- R14 graft: L0 weight prefetch, pinned BEFORE the polls ----
    // Loads issue here; PIN4 forces materialization (waitcnt) pre-poll, so
    // the L2 latency hides under the spin and post-barrier compute is
    // register-resident. Lifetime = this phase only.
    float4 pwi[4][4], pwr[4][4];
    if (L == 0 && p < SEQ) {
#pragma unroll
      for (int g = 0; g < 4; ++g) {
        const int row = (g << 10) + elem;
        const float4* pi = (const float4*)(Wih0 + (size_t)row * HDIM);
        const float4* pr = (const float4*)(Whh0 + (size_t)row * HDIM);
#pragma unroll
        for (int k = 0; k < 4; ++k) {
          pwi[g][k] = pi[(k << 6) + lane];
          pwr[g][k] = pr[(k << 6) + lane];
        }
      }
#pragma unroll
      for (int g = 0; g < 4; ++g)
#pragma unroll
        for (int k = 0; k < 4; ++k) {
          PIN4(pwi[g][k]);
          PIN4(pwr[g][k]);
        }
    }

    // polls exactly as R10: h2 (slack) before h1 (freshest — the real spin)
    float2 vb = make_float2(0, 0);
    if (p >= 2) vb = poll2(h2r + (size_t)(p - 2) * HDIM + (tid << 1));
    float2 va = make_float2(0, 0);
    if (p >= 1) va = poll2(h1r + (size_t)(p - 1) * HDIM + (tid << 1));

    ((float2*)sA[pb])[tid] = va;
    ((float2*)sB[pb])[tid] = vb;
    ((float2*)sX[pb])[tid] = xv;
    __syncthreads();  // the only barrier in the phase (ping-pong buffers)

    const float4* A4 = (const float4*)sA[pb];
    const float4* B4 = (const float4*)sB[pb];
    const float4* X4 = (const float4*)sX[pb];

    if (L == 0) {
      // ---- layer 0: input x[p] (sX), recurrent h1[p-1] (sA) ----
      if (p < SEQ) {
        float4 acc[4];
#pragma unroll
        for (int g = 0; g < 4; ++g) acc[g] = make_float4(0, 0, 0, 0);
#pragma unroll
        for (int k = 0; k < 4; ++k) {
          float4 xf = X4[(k << 6) + lane];
          float4 hf = A4[(k << 6) + lane];
#pragma unroll
          for (int g = 0; g < 4; ++g) {
            FMA4(acc[g], pwi[g][k], xf);
            FMA4(acc[g], pwr[g][k], hf);
          }
        }
        float gi = wave_sum(hsum4(acc[0])) + bias[0];
        float gf = wave_sum(hsum4(acc[1])) + bias[1];
        float gg = wave_sum(hsum4(acc[2])) + bias[2];
        float go = wave_sum(hsum4(acc[3])) + bias[3];
        cell = sigmoidf_(gf) * cell + sigmoidf_(gi) * tanhf(gg);
        float hv = sigmoidf_(go) * tanhf(cell);
        // publish to all nrep replicas (every lane holds hv after wave_sum)
        if (lane < nrep)
          st_u32(h1rep + (size_t)lane * CHAIN + (size_t)p * HDIM + elem,
                 enc(hv));
      }
    } else {
      // ---- layer 1: input h1[p-1] (sA), recurrent h2[p-2] (sB) ----
      if (p >= 1) {
        float4 acc[4];
#pragma unroll
        for (int g = 0; g < 4; ++g) acc[g] = make_float4(0, 0, 0, 0);
#pragma unroll
        for (int k = 0; k < 4; ++k) {
          float4 iv = A4[(k << 6) + lane];
          float4 hf = B4[(k << 6) + lane];
#pragma unroll
          for (int g = 0; g < 4; ++g) {
            FMA4(acc[g], wi1[g][k], iv);
            FMA4(acc[g], wr1[g][k], hf);
          }
        }
        float gi = wave_sum(hsum4(acc[0])) + bias[0];
        float gf = wave_sum(hsum4(acc[1])) + bias[1];
        float gg = wave_sum(hsum4(acc[2])) + bias[2];
        float go = wave_sum(hsum4(acc[3])) + bias[3];
        cell = sigmoidf_(gf) * cell + sigmoidf_(gi) * tanhf(gg);
        float hv = sigmoidf_(go) * tanhf(cell);
        if (lane < nrep)
          st_u32(h2rep + (size_t)lane * CHAIN + (size_t)(p - 1) * HDIM + elem,
                 enc(hv));
      }
    }
    // no trailing barrier: next phase stages into the other LDS buffer
  }

  // ================= FC1: fcb[s][j] = relu(W1[j].h2[s] + b1[j]) ==========
  __syncthreads();  // phase-64 LDS reads done before buffer reuse
  {
    const int s = b >> 2, ch = b & 3;
    float2 v = poll2(h2r + (size_t)s * HDIM + (tid << 1));
    ((float2*)sA[0])[tid] = v;
    __syncthreads();
    const float4* A4 = (const float4*)sA[0];
    for (int t = 0; t < 16; ++t) {
      const int j = (ch << 7) + (q << 4) + t;
      const float4* w4 = (const float4*)(W1 + (size_t)j * HDIM);
      float4 acc = make_float4(0, 0, 0, 0);
#pragma unroll
      for (int k = 0; k < 4; ++k) {
        float4 wv = w4[(k << 6) + lane];
        float4 hv = A4[(k << 6) + lane];
        FMA4(acc, wv, hv);
      }
      float v2 = wave_sum(hsum4(acc));
      if (lane == 0)
        st_u32(fcb + (size_t)s * 512 + j, enc(fmaxf(v2 + b1[j], 0.0f)));
    }
  }

  // ================= FC2: out[s][c] (blocks 0..63, s = b) ================
  if (b < 64) {
    if (tid < 256) {
      float2 v = poll2(fcb + (size_t)b * 512 + (tid << 1));
      ((float2*)sB[0])[tid] = v;
    }
    __syncthreads();
    const float4* B4v = (const float4*)sB[0];
    for (int c = q; c < 27; c += 8) {
      const float4* w4 = (const float4*)(W2 + (size_t)c * 512);
      float4 acc = make_float4(0, 0, 0, 0);
#pragma unroll
      for (int k = 0; k < 2; ++k) {
        float4 wv = w4[(k << 6) + lane];
        float4 hv = B4v[(k << 6) + lane];
        FMA4(acc, wv, hv);
      }
      float v = wave_sum(hsum4(acc));
      if (lane == 0) out[b * 27 + c] = v + b2[c];
    }
  }
}

extern "C" void kernel_launch(void* const* d_in, const int* in_sizes, int n_in,
                              void* d_out, int out_size, void* d_ws,
                              size_t ws_size, hipStream_t stream) {
  (void)in_sizes; (void)n_in; (void)out_size;
  const float* x    = (const float*)d_in[0];
  const float* Wih0 = (const float*)d_in[1];
  const float* Whh0 = (const float*)d_in[2];
  const float* bih0 = (const float*)d_in[3];
  const float* bhh0 = (const float*)d_in[4];
  const float* Wih1 = (const float*)d_in[5];
  const float* Whh1 = (const float*)d_in[6];
  const float* bih1 = (const float*)d_in[7];
  const float* bhh1 = (const float*)d_in[8];
  const float* W1   = (const float*)d_in[9];
  const float* b1   = (const float*)d_in[10];
  const float* W2   = (const float*)d_in[11];
  const float* b2   = (const float*)d_in[12];
  float* out = (float*)d_out;
  unsigned* ws = (unsigned*)d_ws;

  // nrep=8 is the measured fan-out optimum (R10 vs R11); degrade if ws small.
  int nrep = 1;
  for (int r = 8; r >= 1; r >>= 1) {
    size_t need = (2ull * (size_t)r * CHAIN + (size_t)SEQ * 512) * 4ull;
    if (need <= ws_size) { nrep = r; break; }
  }

  // NO memset: the harness's 0xAA poison of d_ws is the protocol's
  // "record not yet written" marker (data-as-flag).
  hipLaunchKernelGGL(lstm_persist, dim3(NBLK), dim3(TPB), 0, stream, x, Wih0,
                     Whh0, bih0, bhh0, Wih1, Whh1, bih1, bhh1, W1, b1, W2, b2,
                     out, ws, nrep);
}

// Round 11
// 463.359 us; speedup vs baseline: 2.7326x; 2.7326x over previous
//
#include <hip/hip_runtime.h>
#include <math.h>

// ---------------------------------------------------------------------------
// Lstm_60748017434907 — R15: R10 champion + wide coherent polls (reader-side
//                            pressure cut; compute/publish untouched).
//
// R14 post-mortem: explicit prefetch+pin made the L0 weight set stream from
// HBM every phase (FETCH 42MB -> 2.07GB = 128KB x 256blk x 64ph exactly);
// compiler-remat'd loads were L2/L3-served all along. Reverted. Ledger:
// R10=278us champion; only confirmed-causal lever = poll/publish fabric
// pressure (R10 -13%); all compute/load-placement perturbations regress.
//
// R15 pushes the reader side only:
//  - R10 spin: all 512 thr poll 1 u64 atomic each, h2 serially BEFORE h1
//    => ~512 in-flight poll streams during the h1 spin, 2 spins deep.
//  - R15 spin: thr 0-255 poll h1, thr 256-511 poll h2 (CONCURRENT), each
//    one 16B coherent load: global_load_dwordx4 sc0 sc1 (L2-bypass; same
//    device-scope path agent atomics use). Atomicity irrelevant — each u32
//    record is independently poison-checked. ~4x fewer poll streams, 2x
//    fewer transactions per round, serial h2->h1 dependency gone.
// Publish (lane<nrep replicas), weights (compiler-remat'd), x staging,
// barrier: byte-identical to R10. nrep=8 (measured optimum).
//
// Protocol: data-as-flag (0xAA poison, enc=+0x55555555), no fences, no
// memset, GUARD bounds every spin (deadlock -> bounded wrong answer).
// ---------------------------------------------------------------------------

#define NBLK 256
#define TPB  512
#define HDIM 1024
#define SEQ  64
#define CHAIN (SEQ * HDIM)
#define GUARD (1L << 20)
#define POISON 0xAAAAAAAAu
#define ENCOFF 0x55555555u

#define FMA4(A, W, Hv)                                                         \
  do {                                                                         \
    (A).x = fmaf((W).x, (Hv).x, (A).x);                                        \
    (A).y = fmaf((W).y, (Hv).y, (A).y);                                        \
    (A).z = fmaf((W).z, (Hv).z, (A).z);                                        \
    (A).w = fmaf((W).w, (Hv).w, (A).w);                                        \
  } while (0)

__device__ __forceinline__ float sigmoidf_(float v) {
  return 1.0f / (1.0f + expf(-v));
}
__device__ __forceinline__ float hsum4(float4 a) {
  return (a.x + a.y) + (a.z + a.w);
}
__device__ __forceinline__ float wave_sum(float v) {
#pragma unroll
  for (int m = 32; m >= 1; m >>= 1) v += __shfl_xor(v, m, 64);
  return v;
}

__device__ __forceinline__ void st_u32(unsigned* p, unsigned v) {
  __hip_atomic_store(p, v, __ATOMIC_RELAXED, __HIP_MEMORY_SCOPE_AGENT);
}
__device__ __forceinline__ unsigned enc(float v) {
  return __float_as_uint(v) + ENCOFF;
}
__device__ __forceinline__ float dec(unsigned u) {
  return __uint_as_float(u - ENCOFF);
}
// poll one u64 record-pair until both halves != poison (atomic path — used
// only in the one-shot FC stages)
__device__ __forceinline__ float2 poll2(const unsigned* p) {
  const unsigned long long* pp = (const unsigned long long*)p;
  unsigned lo, hi;
  long g = 0;
  for (;;) {
    unsigned long long u =
        __hip_atomic_load(pp, __ATOMIC_RELAXED, __HIP_MEMORY_SCOPE_AGENT);
    lo = (unsigned)u;
    hi = (unsigned)(u >> 32);
    if ((lo != POISON) & (hi != POISON)) break;
    __builtin_amdgcn_s_sleep(1);
    if (++g > GUARD) break;  // deadlock -> bounded wrong answer, no hang
  }
  asm volatile("" ::: "memory");
  return make_float2(dec(lo), dec(hi));
}

// R15: poll FOUR records with ONE coherent 16B load. sc0 sc1 = gfx950
// L2-bypassing device-scope load (glc/slc don't assemble on gfx950).
// Tearing is fine: each u32 is an independent data-as-flag record.
__device__ __forceinline__ float4 poll16(const unsigned* p) {
  float4 v;
  long g = 0;
  for (;;) {
    asm volatile("global_load_dwordx4 %0, %1, off sc0 sc1\n\t"
                 "s_waitcnt vmcnt(0)"
                 : "=v"(v)
                 : "v"(p)
                 : "memory");
    const unsigned a = __float_as_uint(v.x), b_ = __float_as_uint(v.y);
    const unsigned c = __float_as_uint(v.z), d = __float_as_uint(v.w);
    if ((a != POISON) & (b_ != POISON) & (c != POISON) & (d != POISON)) break;
    __builtin_amdgcn_s_sleep(1);
    if (++g > GUARD) break;  // deadlock -> bounded wrong answer, no hang
  }
  return make_float4(dec(__float_as_uint(v.x)), dec(__float_as_uint(v.y)),
                     dec(__float_as_uint(v.z)), dec(__float_as_uint(v.w)));
}

__global__ void __launch_bounds__(TPB, 2) lstm_persist(
    const float* __restrict__ x,
    const float* __restrict__ Wih0, const float* __restrict__ Whh0,
    const float* __restrict__ bih0, const float* __restrict__ bhh0,
    const float* __restrict__ Wih1, const float* __restrict__ Whh1,
    const float* __restrict__ bih1, const float* __restrict__ bhh1,
    const float* __restrict__ W1, const float* __restrict__ b1,
    const float* __restrict__ W2, const float* __restrict__ b2,
    float* __restrict__ out, unsigned* ws, int nrep) {
  __shared__ float sA[2][HDIM];  // h1[p-1]
  __shared__ float sB[2][HDIM];  // h2[p-2]
  __shared__ float sX[2][HDIM];  // x[p]

  // ws layout (u32): h1rep[nrep][CHAIN] | h2rep[nrep][CHAIN] | fcb[64*512]
  unsigned* h1rep = ws;
  unsigned* h2rep = ws + (size_t)nrep * CHAIN;
  unsigned* fcb = ws + 2ull * (size_t)nrep * CHAIN;

  const int tid = threadIdx.x;
  const int b = blockIdx.x;
  const int lane = tid & 63;
  const int q = tid >> 6;             // 0..7
  const int L = q >> 2;               // 0: layer0 waves, 1: layer1 waves
  const int elem = (b << 2) + (q & 3);

  // this block's poll replica (nrep pow2; nrep=8 => reader set per XCD)
  const int rep = b & (nrep - 1);
  unsigned* h1r = h1rep + (size_t)rep * CHAIN;
  unsigned* h2r = h2rep + (size_t)rep * CHAIN;

  // ---- weights: wave holds all 4 gate rows of ONE layer for its elem ----
  // (compiler remats per phase from L2/L3 — R14 proved that's the GOOD case)
  const float* Wih = L ? Wih1 : Wih0;
  const float* Whh = L ? Whh1 : Whh0;
  const float* bi = L ? bih1 : bih0;
  const float* bh = L ? bhh1 : bhh0;

  float4 wi[4][4], wr[4][4];
  float bias[4];
#pragma unroll
  for (int g = 0; g < 4; ++g) {
    const int row = (g << 10) + elem;
    bias[g] = bi[row] + bh[row];
    const float4* pi = (const float4*)(Wih + (size_t)row * HDIM);
    const float4* pr = (const float4*)(Whh + (size_t)row * HDIM);
#pragma unroll
    for (int k = 0; k < 4; ++k) {
      wi[g][k] = pi[(k << 6) + lane];
      wr[g][k] = pr[(k << 6) + lane];
    }
  }

  float cell = 0.0f;  // wave-uniform cell state (this wave's layer+elem)

  // ================= pipelined phases p = 0..64 =================
  for (int p = 0; p <= SEQ; ++p) {
    const int pb = p & 1;
    // x[p] issued first — its vmcnt wait is the natural pre-poll backoff
    // (R13 lesson: removing it regresses).
    float2 xv = make_float2(0, 0);
    if (p < SEQ)
      xv = ((const float2*)x)[(size_t)(p * 256 + 255) * 512 + tid];

    // ---- R15 split spin: thr 0-255 own h1, thr 256-511 own h2 ----
    if (tid < 256) {
      float4 va4 = make_float4(0, 0, 0, 0);
      if (p >= 1) va4 = poll16(h1r + (size_t)(p - 1) * HDIM + (tid << 2));
      ((float4*)sA[pb])[tid] = va4;
    } else {
      const int t = tid - 256;
      float4 vb4 = make_float4(0, 0, 0, 0);
      if (p >= 2) vb4 = poll16(h2r + (size_t)(p - 2) * HDIM + (t << 2));
      ((float4*)sB[pb])[t] = vb4;
    }
    ((float2*)sX[pb])[tid] = xv;
    __syncthreads();  // the only barrier in the phase (ping-pong buffers)

    const float4* A4 = (const float4*)sA[pb];
    const float4* B4 = (const float4*)sB[pb];
    const float4* X4 = (const float4*)sX[pb];

    if (L == 0) {
      // ---- layer 0: input x[p] (sX), recurrent h1[p-1] (sA) ----
      if (p < SEQ) {
        float4 acc[4];
#pragma unroll
        for (int g = 0; g < 4; ++g) acc[g] = make_float4(0, 0, 0, 0);
#pragma unroll
        for (int k = 0; k < 4; ++k) {
          float4 xf = X4[(k << 6) + lane];
          float4 hf = A4[(k << 6) + lane];
#pragma unroll
          for (int g = 0; g < 4; ++g) {
            FMA4(acc[g], wi[g][k], xf);
            FMA4(acc[g], wr[g][k], hf);
          }
        }
        float gi = wave_sum(hsum4(acc[0])) + bias[0];
        float gf = wave_sum(hsum4(acc[1])) + bias[1];
        float gg = wave_sum(hsum4(acc[2])) + bias[2];
        float go = wave_sum(hsum4(acc[3])) + bias[3];
        cell = sigmoidf_(gf) * cell + sigmoidf_(gi) * tanhf(gg);
        float hv = sigmoidf_(go) * tanhf(cell);
        // publish to all nrep replicas (every lane holds hv after wave_sum)
        if (lane < nrep)
          st_u32(h1rep + (size_t)lane * CHAIN + (size_t)p * HDIM + elem,
                 enc(hv));
      }
    } else {
      // ---- layer 1: input h1[p-1] (sA), recurrent h2[p-2] (sB) ----
      if (p >= 1) {
        float4 acc[4];
#pragma unroll
        for (int g = 0; g < 4; ++g) acc[g] = make_float4(0, 0, 0, 0);
#pragma unroll
        for (int k = 0; k < 4; ++k) {
          float4 iv = A4[(k << 6) + lane];
          float4 hf = B4[(k << 6) + lane];
#pragma unroll
          for (int g = 0; g < 4; ++g) {
            FMA4(acc[g], wi[g][k], iv);
            FMA4(acc[g], wr[g][k], hf);
          }
        }
        float gi = wave_sum(hsum4(acc[0])) + bias[0];
        float gf = wave_sum(hsum4(acc[1])) + bias[1];
        float gg = wave_sum(hsum4(acc[2])) + bias[2];
        float go = wave_sum(hsum4(acc[3])) + bias[3];
        cell = sigmoidf_(gf) * cell + sigmoidf_(gi) * tanhf(gg);
        float hv = sigmoidf_(go) * tanhf(cell);
        if (lane < nrep)
          st_u32(h2rep + (size_t)lane * CHAIN + (size_t)(p - 1) * HDIM + elem,
                 enc(hv));
      }
    }
    // no trailing barrier: next phase stages into the other LDS buffer
  }

  // ================= FC1: fcb[s][j] = relu(W1[j].h2[s] + b1[j]) ==========
  __syncthreads();  // phase-64 LDS reads done before buffer reuse
  {
    const int s = b >> 2, ch = b & 3;
    float2 v = poll2(h2r + (size_t)s * HDIM + (tid << 1));
    ((float2*)sA[0])[tid] = v;
    __syncthreads();
    const float4* A4 = (const float4*)sA[0];
    for (int t = 0; t < 16; ++t) {
      const int j = (ch << 7) + (q << 4) + t;
      const float4* w4 = (const float4*)(W1 + (size_t)j * HDIM);
      float4 acc = make_float4(0, 0, 0, 0);
#pragma unroll
      for (int k = 0; k < 4; ++k) {
        float4 wv = w4[(k << 6) + lane];
        float4 hv = A4[(k << 6) + lane];
        FMA4(acc, wv, hv);
      }
      float v2 = wave_sum(hsum4(acc));
      if (lane == 0)
        st_u32(fcb + (size_t)s * 512 + j, enc(fmaxf(v2 + b1[j], 0.0f)));
    }
  }

  // ================= FC2: out[s][c] (blocks 0..63, s = b) ================
  if (b < 64) {
    if (tid < 256) {
      float2 v = poll2(fcb + (size_t)b * 512 + (tid << 1));
      ((float2*)sB[0])[tid] = v;
    }
    __syncthreads();
    const float4* B4v = (const float4*)sB[0];
    for (int c = q; c < 27; c += 8) {
      const float4* w4 = (const float4*)(W2 + (size_t)c * 512);
      float4 acc = make_float4(0, 0, 0, 0);
#pragma unroll
      for (int k = 0; k < 2; ++k) {
        float4 wv = w4[(k << 6) + lane];
        float4 hv = B4v[(k << 6) + lane];
        FMA4(acc, wv, hv);
      }
      float v = wave_sum(hsum4(acc));
      if (lane == 0) out[b * 27 + c] = v + b2[c];
    }
  }
}

extern "C" void kernel_launch(void* const* d_in, const int* in_sizes, int n_in,
                              void* d_out, int out_size, void* d_ws,
                              size_t ws_size, hipStream_t stream) {
  (void)in_sizes; (void)n_in; (void)out_size;
  const float* x    = (const float*)d_in[0];
  const float* Wih0 = (const float*)d_in[1];
  const float* Whh0 = (const float*)d_in[2];
  const float* bih0 = (const float*)d_in[3];
  const float* bhh0 = (const float*)d_in[4];
  const float* Wih1 = (const float*)d_in[5];
  const float* Whh1 = (const float*)d_in[6];
  const float* bih1 = (const float*)d_in[7];
  const float* bhh1 = (const float*)d_in[8];
  const float* W1   = (const float*)d_in[9];
  const float* b1   = (const float*)d_in[10];
  const float* W2   = (const float*)d_in[11];
  const float* b2   = (const float*)d_in[12];
  float* out = (float*)d_out;
  unsigned* ws = (unsigned*)d_ws;

  // nrep=8 is the measured fan-out optimum (R10 vs R11); degrade if ws small.
  int nrep = 1;
  for (int r = 8; r >= 1; r >>= 1) {
    size_t need = (2ull * (size_t)r * CHAIN + (size_t)SEQ * 512) * 4ull;
    if (need <= ws_size) { nrep = r; break; }
  }

  // NO memset: the harness's 0xAA poison of d_ws is the protocol's
  // "record not yet written" marker (data-as-flag).
  hipLaunchKernelGGL(lstm_persist, dim3(NBLK), dim3(TPB), 0, stream, x, Wih0,
                     Whh0, bih0, bhh0, Wih1, Whh1, bih1, bhh1, W1, b1, W2, b2,
                     out, ws, nrep);
}